// Round 9
// baseline (637.507 us; speedup 1.0000x reference)
//
#include <hip/hip_runtime.h>
#include <hip/hip_bf16.h>
#include <math.h>

#define BB 16
#define SS 2048
#define DD 128
#define BQ 64      // q rows per block (4 q-groups x 16)
#define BK 64      // keys per tile
#define NT (SS / BK)   // 32 key tiles
#define PLD 72     // P LDS row stride (bf16)
#define VLD 72
#define NELEM (BB * SS * DD)   // 4194304 per tensor

typedef __attribute__((ext_vector_type(8))) __bf16 bf16x8;
typedef __attribute__((ext_vector_type(4))) __bf16 bf16x4;
typedef __attribute__((ext_vector_type(4))) float f32x4;

// ---------- prep 1: q*scale and k -> bf16 row-major ----------
__global__ __launch_bounds__(256)
void prep_qk(const float* __restrict__ q, const float* __restrict__ k,
             __bf16* __restrict__ qs, __bf16* __restrict__ kb) {
  const int NCH = NELEM / 8;
  int g = blockIdx.x * 256 + threadIdx.x;  // 0 .. 2*NCH-1
  const float* src;
  __bf16* dst;
  float sc;
  if (g < NCH) { src = q; dst = qs; sc = 0.08838834764831845f; }
  else         { g -= NCH; src = k; dst = kb; sc = 1.0f; }
  const float4* p = (const float4*)(src + (size_t)g * 8);
  float4 a = p[0], b = p[1];
  bf16x8 w;
  w[0] = (__bf16)(a.x * sc); w[1] = (__bf16)(a.y * sc);
  w[2] = (__bf16)(a.z * sc); w[3] = (__bf16)(a.w * sc);
  w[4] = (__bf16)(b.x * sc); w[5] = (__bf16)(b.y * sc);
  w[6] = (__bf16)(b.z * sc); w[7] = (__bf16)(b.w * sc);
  ((bf16x8*)dst)[g] = w;
}

// ---------- prep 2: v -> bf16 transposed [b][d][s] ----------
__global__ __launch_bounds__(256)
void prep_vt(const float* __restrict__ v, __bf16* __restrict__ vt) {
  __shared__ __align__(16) __bf16 lT[DD * VLD];
  const int tid = threadIdx.x;
  const int b = blockIdx.y;
  const int s0 = blockIdx.x * 64;

  const int key = tid >> 2;
  const int dc = (tid & 3) * 32;
  const float* src = v + ((size_t)b * SS + s0 + key) * DD + dc;
#pragma unroll
  for (int i = 0; i < 8; ++i) {
    float4 f = ((const float4*)src)[i];
    lT[(dc + i * 4 + 0) * VLD + key] = (__bf16)f.x;
    lT[(dc + i * 4 + 1) * VLD + key] = (__bf16)f.y;
    lT[(dc + i * 4 + 2) * VLD + key] = (__bf16)f.z;
    lT[(dc + i * 4 + 3) * VLD + key] = (__bf16)f.w;
  }
  __syncthreads();
#pragma unroll
  for (int j = 0; j < 4; ++j) {
    int c = tid + j * 256;          // 1024 chunks: 128 d x 8 s-chunks
    int d = c >> 3, sc2 = c & 7;
    bf16x8 w = *(const bf16x8*)(lT + d * VLD + sc2 * 8);
    *(bf16x8*)(vt + ((size_t)b * DD + d) * SS + s0 + sc2 * 8) = w;
  }
}

// ============================================================
// Fused attention, split-K 8-wave blocks:
//   waves 0-3: q-groups 0-3, keys [0,1024)
//   waves 4-7: q-groups 0-3, keys [1024,2048)
// Swapped-operand QK (mfma(K,Q)) -> lane owns a 16-key slice of ONE
// q-row; softmax reduce = 2 shuffles. attn written directly from f32
// regs (plain cached stores -> full-line write-combining in L2).
// (m,l) and ctx partials merged through LDS (3 barriers total).
// ============================================================
__global__ __launch_bounds__(512, 4)
void attn_fused(const __bf16* __restrict__ qs, const __bf16* __restrict__ kb,
                const __bf16* __restrict__ vt, float* __restrict__ ctx,
                float* __restrict__ attn) {
  __shared__ __align__(16) __bf16 lP[8][16 * PLD];     // 18432 B (wave-private)
  __shared__ __align__(16) float lMrg[4][16][130];     // 33280 B
  __shared__ float sM[8][16];                          //   512 B
  __shared__ float sL[8][16];                          //   512 B

  const int tid  = threadIdx.x;
  const int wave = tid >> 6;        // 0..7
  const int half = wave >> 2;       // key half
  const int g    = wave & 3;        // q-group
  const int lane = tid & 63;
  const int quad = lane >> 4;
  const int l16  = lane & 15;

  // XCD-aware mapping: 2 batches per XCD -> K+V (2 MiB bf16) L2-resident.
  const int d0  = blockIdx.x;            // 0..511
  const int xcd = d0 & 7;
  const int j   = d0 >> 3;               // 0..63
  const int b   = 2 * xcd + (j & 1);     // batch
  const int q0  = (j >> 1) * BQ;         // q-block origin

  const int qrow = q0 + g * 16 + l16;    // this lane's q-row
  const int ktLo = half * (NT / 2);
  const int ktHi = ktLo + NT / 2;

  const __bf16* kbase = kb + (size_t)b * SS * DD;
  const __bf16* vbase = vt + (size_t)b * DD * SS;

  // Q fragment (B-operand): n = l16 = q-row, k = ks*32 + quad*8 + j
  bf16x8 aq[4];
  {
    const __bf16* qp = qs + ((size_t)b * SS + qrow) * DD;
#pragma unroll
    for (int ks = 0; ks < 4; ++ks)
      aq[ks] = *(const bf16x8*)(qp + ks * 32 + quad * 8);
  }

  // ================= Phase 1: softmax stats (partial, this wave's keys) ===
  float m = -1e30f, l = 0.0f;
  for (int kt = ktLo; kt < ktHi; ++kt) {
    const __bf16* kt0 = kbase + (size_t)(kt * BK) * DD;
    f32x4 sacc[4];
#pragma unroll
    for (int nb = 0; nb < 4; ++nb) sacc[nb] = (f32x4){0.f, 0.f, 0.f, 0.f};
#pragma unroll
    for (int nb = 0; nb < 4; ++nb)
#pragma unroll
      for (int ks = 0; ks < 4; ++ks) {
        bf16x8 ak = *(const bf16x8*)(kt0 + (size_t)(nb * 16 + l16) * DD + ks * 32 + quad * 8);
        sacc[nb] = __builtin_amdgcn_mfma_f32_16x16x32_bf16(ak, aq[ks], sacc[nb], 0, 0, 0);
      }
    float tm = -1e30f;
#pragma unroll
    for (int nb = 0; nb < 4; ++nb)
#pragma unroll
      for (int r = 0; r < 4; ++r) tm = fmaxf(tm, sacc[nb][r]);
    tm = fmaxf(tm, __shfl_xor(tm, 16));
    tm = fmaxf(tm, __shfl_xor(tm, 32));
    float mnew = fmaxf(m, tm);
    float ps = 0.0f;
#pragma unroll
    for (int nb = 0; nb < 4; ++nb)
#pragma unroll
      for (int r = 0; r < 4; ++r) ps += __expf(sacc[nb][r] - mnew);
    ps += __shfl_xor(ps, 16);
    ps += __shfl_xor(ps, 32);
    l = l * __expf(m - mnew) + ps;
    m = mnew;
  }

  // merge (m,l) across the two key-halves of this q-group
  if (quad == 0) { sM[wave][l16] = m; sL[wave][l16] = l; }
  __syncthreads();
  float mu;
  {
    float m0 = sM[g][l16],     l0 = sL[g][l16];
    float m1 = sM[g + 4][l16], l1 = sL[g + 4][l16];
    float mn = fmaxf(m0, m1);
    float lt = l0 * __expf(m0 - mn) + l1 * __expf(m1 - mn);
    mu = mn + __logf(lt);
  }

  // ================= Phase 2: attn write + PV (this wave's keys) =========
  f32x4 cacc[8];
#pragma unroll
  for (int nb = 0; nb < 8; ++nb) cacc[nb] = (f32x4){0.f, 0.f, 0.f, 0.f};

  __bf16* myP = lP[wave];
  float* arow = attn + ((size_t)b * SS + qrow) * (size_t)SS + quad * 4;

  for (int kt = ktLo; kt < ktHi; ++kt) {
    const int kk0 = kt * BK;
    const __bf16* kt0 = kbase + (size_t)kk0 * DD;
    f32x4 sacc[4];
#pragma unroll
    for (int nb = 0; nb < 4; ++nb) sacc[nb] = (f32x4){0.f, 0.f, 0.f, 0.f};
#pragma unroll
    for (int nb = 0; nb < 4; ++nb)
#pragma unroll
      for (int ks = 0; ks < 4; ++ks) {
        bf16x8 ak = *(const bf16x8*)(kt0 + (size_t)(nb * 16 + l16) * DD + ks * 32 + quad * 8);
        sacc[nb] = __builtin_amdgcn_mfma_f32_16x16x32_bf16(ak, aq[ks], sacc[nb], 0, 0, 0);
      }

    // p = exp(s - mu): write attn directly (plain cached f32 stores,
    // each row gets 256B contiguous per tile -> full-line writeback),
    // and stash bf16 P in wave-private LDS for PV.
#pragma unroll
    for (int nb = 0; nb < 4; ++nb) {
      f32x4 o;
      o[0] = __expf(sacc[nb][0] - mu);
      o[1] = __expf(sacc[nb][1] - mu);
      o[2] = __expf(sacc[nb][2] - mu);
      o[3] = __expf(sacc[nb][3] - mu);
      *(f32x4*)(arow + kk0 + nb * 16) = o;
      bf16x4 pk;
      pk[0] = (__bf16)o[0]; pk[1] = (__bf16)o[1];
      pk[2] = (__bf16)o[2]; pk[3] = (__bf16)o[3];
      *(bf16x4*)(myP + l16 * PLD + nb * 16 + quad * 4) = pk;
    }
    // PV: wave-private lP -> A-frag (same-wave producer/consumer, no barrier)
#pragma unroll
    for (int kk = 0; kk < 2; ++kk) {
      bf16x8 ap = *(const bf16x8*)(myP + l16 * PLD + kk * 32 + quad * 8);
#pragma unroll
      for (int nb = 0; nb < 8; ++nb) {
        bf16x8 bv = *(const bf16x8*)(vbase + (size_t)(nb * 16 + l16) * SS + kk0 + kk * 32 + quad * 8);
        cacc[nb] = __builtin_amdgcn_mfma_f32_16x16x32_bf16(ap, bv, cacc[nb], 0, 0, 0);
      }
    }
  }

  // ================= merge ctx partials across key-halves =================
  if (half == 1) {
#pragma unroll
    for (int nb = 0; nb < 8; ++nb)
#pragma unroll
      for (int r = 0; r < 4; ++r)
        lMrg[g][quad * 4 + r][nb * 16 + l16] = cacc[nb][r];
  }
  __syncthreads();
  if (half == 0) {
#pragma unroll
    for (int nb = 0; nb < 8; ++nb)
#pragma unroll
      for (int r = 0; r < 4; ++r) {
        float vsum = cacc[nb][r] + lMrg[g][quad * 4 + r][nb * 16 + l16];
        ctx[((size_t)b * SS + q0 + g * 16 + quad * 4 + r) * DD + nb * 16 + l16] = vsum;
      }
  }
}

extern "C" void kernel_launch(void* const* d_in, const int* in_sizes, int n_in,
                              void* d_out, int out_size, void* d_ws, size_t ws_size,
                              hipStream_t stream) {
  const float* q = (const float*)d_in[0];
  const float* k = (const float*)d_in[1];
  const float* v = (const float*)d_in[2];
  float* ctx  = (float*)d_out;
  float* attn = ctx + (size_t)BB * SS * DD;

  __bf16* qs = (__bf16*)d_ws;
  __bf16* kb = qs + (size_t)NELEM;
  __bf16* vt = kb + (size_t)NELEM;

  prep_qk<<<2 * (NELEM / 8) / 256, 256, 0, stream>>>(q, k, qs, kb);
  prep_vt<<<dim3(SS / 64, BB), 256, 0, stream>>>(v, vt);
  attn_fused<<<dim3(512), 512, 0, stream>>>(qs, kb, vt, ctx, attn);
}

// Round 12
// 634.423 us; speedup vs baseline: 1.0049x; 1.0049x over previous
//
#include <hip/hip_runtime.h>
#include <hip/hip_bf16.h>
#include <math.h>

#define BB 16
#define SS 2048
#define DD 128
#define BQ 64      // q rows per block (4 q-groups x 16)
#define BK 64      // keys per tile
#define NT (SS / BK)   // 32 key tiles
#define PLD 72     // bf16 P LDS row stride
#define PFLD 72    // f32 P staging row stride (bank-minimal, 16B-aligned)
#define VLD 72
#define NELEM (BB * SS * DD)   // 4194304 per tensor

typedef __attribute__((ext_vector_type(8))) __bf16 bf16x8;
typedef __attribute__((ext_vector_type(4))) __bf16 bf16x4;
typedef __attribute__((ext_vector_type(4))) float f32x4;

// ---------- prep 1: q*scale and k -> bf16 row-major ----------
__global__ __launch_bounds__(256)
void prep_qk(const float* __restrict__ q, const float* __restrict__ k,
             __bf16* __restrict__ qs, __bf16* __restrict__ kb) {
  const int NCH = NELEM / 8;
  int g = blockIdx.x * 256 + threadIdx.x;  // 0 .. 2*NCH-1
  const float* src;
  __bf16* dst;
  float sc;
  if (g < NCH) { src = q; dst = qs; sc = 0.08838834764831845f; }
  else         { g -= NCH; src = k; dst = kb; sc = 1.0f; }
  const float4* p = (const float4*)(src + (size_t)g * 8);
  float4 a = p[0], b = p[1];
  bf16x8 w;
  w[0] = (__bf16)(a.x * sc); w[1] = (__bf16)(a.y * sc);
  w[2] = (__bf16)(a.z * sc); w[3] = (__bf16)(a.w * sc);
  w[4] = (__bf16)(b.x * sc); w[5] = (__bf16)(b.y * sc);
  w[6] = (__bf16)(b.z * sc); w[7] = (__bf16)(b.w * sc);
  ((bf16x8*)dst)[g] = w;
}

// ---------- prep 2: v -> bf16 transposed [b][d][s] ----------
__global__ __launch_bounds__(256)
void prep_vt(const float* __restrict__ v, __bf16* __restrict__ vt) {
  __shared__ __align__(16) __bf16 lT[DD * VLD];
  const int tid = threadIdx.x;
  const int b = blockIdx.y;
  const int s0 = blockIdx.x * 64;

  const int key = tid >> 2;
  const int dc = (tid & 3) * 32;
  const float* src = v + ((size_t)b * SS + s0 + key) * DD + dc;
#pragma unroll
  for (int i = 0; i < 8; ++i) {
    float4 f = ((const float4*)src)[i];
    lT[(dc + i * 4 + 0) * VLD + key] = (__bf16)f.x;
    lT[(dc + i * 4 + 1) * VLD + key] = (__bf16)f.y;
    lT[(dc + i * 4 + 2) * VLD + key] = (__bf16)f.z;
    lT[(dc + i * 4 + 3) * VLD + key] = (__bf16)f.w;
  }
  __syncthreads();
#pragma unroll
  for (int j = 0; j < 4; ++j) {
    int c = tid + j * 256;          // 1024 chunks: 128 d x 8 s-chunks
    int d = c >> 3, sc2 = c & 7;
    bf16x8 w = *(const bf16x8*)(lT + d * VLD + sc2 * 8);
    *(bf16x8*)(vt + ((size_t)b * DD + d) * SS + s0 + sc2 * 8) = w;
  }
}

// ============================================================
// Fused attention, split-K 8-wave blocks (structure = round 9).
// SINGLE DELTA vs round 9: attn stores are now FULL-LINE coalesced.
// P (f32) is staged in LDS [16][PFLD], then stored with a remapped
// wave: 16 lanes x 16B per row, 4 rows per instruction -> 256B
// contiguous per row = full 128B L2 lines (was 16 rows x 64B
// partial-line segments). PV / QK / split-K unchanged.
// f32 staging buffer unions with the epilogue ctx-merge buffer.
// ============================================================
__global__ __launch_bounds__(512, 4)
void attn_fused(const __bf16* __restrict__ qs, const __bf16* __restrict__ kb,
                const __bf16* __restrict__ vt, float* __restrict__ ctx,
                float* __restrict__ attn) {
  __shared__ __align__(16) __bf16 lP[8][16 * PLD];      // 18432 B (wave-private)
  __shared__ __align__(16) float lBig[8][16][PFLD];     // 36864 B: f32 P staging,
                                                        // epilogue: ctx merge (union)
  __shared__ float sM[8][16];                           //   512 B
  __shared__ float sL[8][16];                           //   512 B

  const int tid  = threadIdx.x;
  const int wave = tid >> 6;        // 0..7
  const int half = wave >> 2;       // key half
  const int g    = wave & 3;        // q-group
  const int lane = tid & 63;
  const int quad = lane >> 4;
  const int l16  = lane & 15;

  // XCD-aware mapping: 2 batches per XCD -> K+V (2 MiB bf16) L2-resident.
  const int d0  = blockIdx.x;            // 0..511
  const int xcd = d0 & 7;
  const int j   = d0 >> 3;               // 0..63
  const int b   = 2 * xcd + (j & 1);     // batch
  const int q0  = (j >> 1) * BQ;         // q-block origin

  const int qrow = q0 + g * 16 + l16;    // this lane's q-row
  const int ktLo = half * (NT / 2);
  const int ktHi = ktLo + NT / 2;

  const __bf16* kbase = kb + (size_t)b * SS * DD;
  const __bf16* vbase = vt + (size_t)b * DD * SS;

  // Q fragment (B-operand): n = l16 = q-row, k = ks*32 + quad*8 + j
  bf16x8 aq[4];
  {
    const __bf16* qp = qs + ((size_t)b * SS + qrow) * DD;
#pragma unroll
    for (int ks = 0; ks < 4; ++ks)
      aq[ks] = *(const bf16x8*)(qp + ks * 32 + quad * 8);
  }

  // ================= Phase 1: softmax stats (partial, this wave's keys) ===
  float m = -1e30f, l = 0.0f;
  for (int kt = ktLo; kt < ktHi; ++kt) {
    const __bf16* kt0 = kbase + (size_t)(kt * BK) * DD;
    f32x4 sacc[4];
#pragma unroll
    for (int nb = 0; nb < 4; ++nb) sacc[nb] = (f32x4){0.f, 0.f, 0.f, 0.f};
#pragma unroll
    for (int nb = 0; nb < 4; ++nb)
#pragma unroll
      for (int ks = 0; ks < 4; ++ks) {
        bf16x8 ak = *(const bf16x8*)(kt0 + (size_t)(nb * 16 + l16) * DD + ks * 32 + quad * 8);
        sacc[nb] = __builtin_amdgcn_mfma_f32_16x16x32_bf16(ak, aq[ks], sacc[nb], 0, 0, 0);
      }
    float tm = -1e30f;
#pragma unroll
    for (int nb = 0; nb < 4; ++nb)
#pragma unroll
      for (int r = 0; r < 4; ++r) tm = fmaxf(tm, sacc[nb][r]);
    tm = fmaxf(tm, __shfl_xor(tm, 16));
    tm = fmaxf(tm, __shfl_xor(tm, 32));
    float mnew = fmaxf(m, tm);
    float ps = 0.0f;
#pragma unroll
    for (int nb = 0; nb < 4; ++nb)
#pragma unroll
      for (int r = 0; r < 4; ++r) ps += __expf(sacc[nb][r] - mnew);
    ps += __shfl_xor(ps, 16);
    ps += __shfl_xor(ps, 32);
    l = l * __expf(m - mnew) + ps;
    m = mnew;
  }

  // merge (m,l) across the two key-halves of this q-group
  if (quad == 0) { sM[wave][l16] = m; sL[wave][l16] = l; }
  __syncthreads();
  float mu;
  {
    float m0 = sM[g][l16],     l0 = sL[g][l16];
    float m1 = sM[g + 4][l16], l1 = sL[g + 4][l16];
    float mn = fmaxf(m0, m1);
    float lt = l0 * __expf(m0 - mn) + l1 * __expf(m1 - mn);
    mu = mn + __logf(lt);
  }

  // ================= Phase 2: attn write + PV (this wave's keys) =========
  f32x4 cacc[8];
#pragma unroll
  for (int nb = 0; nb < 8; ++nb) cacc[nb] = (f32x4){0.f, 0.f, 0.f, 0.f};

  __bf16* myP = lP[wave];
  float (*myPf)[PFLD] = lBig[wave];

  for (int kt = ktLo; kt < ktHi; ++kt) {
    const int kk0 = kt * BK;
    const __bf16* kt0 = kbase + (size_t)kk0 * DD;
    f32x4 sacc[4];
#pragma unroll
    for (int nb = 0; nb < 4; ++nb) sacc[nb] = (f32x4){0.f, 0.f, 0.f, 0.f};
#pragma unroll
    for (int nb = 0; nb < 4; ++nb)
#pragma unroll
      for (int ks = 0; ks < 4; ++ks) {
        bf16x8 ak = *(const bf16x8*)(kt0 + (size_t)(nb * 16 + l16) * DD + ks * 32 + quad * 8);
        sacc[nb] = __builtin_amdgcn_mfma_f32_16x16x32_bf16(ak, aq[ks], sacc[nb], 0, 0, 0);
      }

    // p = exp(s - mu): stage f32 P in LDS (bank-minimal stride 72),
    // and bf16 P in wave-private lP for PV (unchanged).
#pragma unroll
    for (int nb = 0; nb < 4; ++nb) {
      f32x4 o;
      o[0] = __expf(sacc[nb][0] - mu);
      o[1] = __expf(sacc[nb][1] - mu);
      o[2] = __expf(sacc[nb][2] - mu);
      o[3] = __expf(sacc[nb][3] - mu);
      *(f32x4*)(&myPf[l16][nb * 16 + quad * 4]) = o;
      bf16x4 pk;
      pk[0] = (__bf16)o[0]; pk[1] = (__bf16)o[1];
      pk[2] = (__bf16)o[2]; pk[3] = (__bf16)o[3];
      *(bf16x4*)(myP + l16 * PLD + nb * 16 + quad * 4) = pk;
    }

    // attn write, FULL-LINE coalesced: per instr, 16 lanes x 16B per row,
    // 4 rows -> each row gets 256B contiguous (2 full 128B lines).
    // Same-wave LDS producer/consumer -> compiler inserts lgkmcnt, no barrier.
#pragma unroll
    for (int s = 0; s < 4; ++s) {
      const int row = s * 4 + quad;         // 0..15
      const int c4  = l16 * 4;              // 0,4,...,60
      f32x4 w = *(const f32x4*)(&myPf[row][c4]);
      *(f32x4*)(attn + ((size_t)b * SS + q0 + g * 16 + row) * (size_t)SS + kk0 + c4) = w;
    }

    // PV: wave-private lP -> A-frag (unchanged)
#pragma unroll
    for (int kk = 0; kk < 2; ++kk) {
      bf16x8 ap = *(const bf16x8*)(myP + l16 * PLD + kk * 32 + quad * 8);
#pragma unroll
      for (int nb = 0; nb < 8; ++nb) {
        bf16x8 bv = *(const bf16x8*)(vbase + (size_t)(nb * 16 + l16) * SS + kk0 + kk * 32 + quad * 8);
        cacc[nb] = __builtin_amdgcn_mfma_f32_16x16x32_bf16(ap, bv, cacc[nb], 0, 0, 0);
      }
    }
  }

  // ================= merge ctx partials across key-halves =================
  // lBig is re-purposed as the merge buffer; barrier first so every wave is
  // done with its f32 P staging region.
  __syncthreads();
  float* mrg = (float*)lBig;   // [4][16][130] layout, 33280 B < 36864 B
  if (half == 1) {
#pragma unroll
    for (int nb = 0; nb < 8; ++nb)
#pragma unroll
      for (int r = 0; r < 4; ++r)
        mrg[((g * 16) + quad * 4 + r) * 130 + nb * 16 + l16] = cacc[nb][r];
  }
  __syncthreads();
  if (half == 0) {
#pragma unroll
    for (int nb = 0; nb < 8; ++nb)
#pragma unroll
      for (int r = 0; r < 4; ++r) {
        float vsum = cacc[nb][r] + mrg[((g * 16) + quad * 4 + r) * 130 + nb * 16 + l16];
        ctx[((size_t)b * SS + q0 + g * 16 + quad * 4 + r) * DD + nb * 16 + l16] = vsum;
      }
  }
}

extern "C" void kernel_launch(void* const* d_in, const int* in_sizes, int n_in,
                              void* d_out, int out_size, void* d_ws, size_t ws_size,
                              hipStream_t stream) {
  const float* q = (const float*)d_in[0];
  const float* k = (const float*)d_in[1];
  const float* v = (const float*)d_in[2];
  float* ctx  = (float*)d_out;
  float* attn = ctx + (size_t)BB * SS * DD;

  __bf16* qs = (__bf16*)d_ws;
  __bf16* kb = qs + (size_t)NELEM;
  __bf16* vt = kb + (size_t)NELEM;

  prep_qk<<<2 * (NELEM / 8) / 256, 256, 0, stream>>>(q, k, qs, kb);
  prep_vt<<<dim3(SS / 64, BB), 256, 0, stream>>>(v, vt);
  attn_fused<<<dim3(512), 512, 0, stream>>>(qs, kb, vt, ctx, attn);
}